// Round 2
// baseline (368.097 us; speedup 1.0000x reference)
//
#include <hip/hip_runtime.h>

// ---------------------------------------------------------------------------
// SAGE 3-layer GNN, fp32.
//   Per layer: S = X@W_self + b ; P = X@W_neigh  (one dual GEMM kernel)
//              h[i] = act( S[i] + (sum_{j in N_in(i)} P[j]) / max(deg_i,1) )
//   CSR (deg, row_start, edge_src sorted by dst) built once, reused 3 layers.
//   Readout fused into layer-3 aggregation (global atomics into 16x64 sums).
//
// R1: agg_kernel restructured for memory-level parallelism. Old version used
// 12 VGPRs -> compiler serialized every 4B gather (VALUBusy 2.9%, 135us,
// ~50x above the L2-BW floor). New layout: wave = 4 edge-groups x 16 lanes,
// float4 per lane, index loads software-pipelined one iteration ahead.
// ---------------------------------------------------------------------------

#define DH 64
#define NG 16

__global__ void deg_count_kernel(const int* __restrict__ dst, int* __restrict__ deg, int E) {
    int i = blockIdx.x * blockDim.x + threadIdx.x;
    if (i < E) atomicAdd(&deg[dst[i]], 1);
}

// single-block exclusive prefix scan over deg -> row_start (and cursor copy)
__global__ void scan_kernel(const int* __restrict__ deg, int* __restrict__ row_start,
                            int* __restrict__ cursor, int M) {
    __shared__ int sdata[1024];
    __shared__ int s_base;
    int tid = threadIdx.x;
    if (tid == 0) s_base = 0;
    __syncthreads();
    for (int base = 0; base < M; base += 1024) {
        int v = (base + tid < M) ? deg[base + tid] : 0;
        sdata[tid] = v;
        __syncthreads();
        for (int off = 1; off < 1024; off <<= 1) {
            int t = (tid >= off) ? sdata[tid - off] : 0;
            __syncthreads();
            sdata[tid] += t;
            __syncthreads();
        }
        int excl = sdata[tid] - v;
        if (base + tid < M) {
            int rs = s_base + excl;
            row_start[base + tid] = rs;
            cursor[base + tid] = rs;
        }
        __syncthreads();
        if (tid == 1023) s_base += sdata[1023];
        __syncthreads();
    }
    if (tid == 0) row_start[M] = s_base;
}

__global__ void scatter_kernel(const int* __restrict__ src, const int* __restrict__ dst,
                               int* __restrict__ cursor, int* __restrict__ edge_src, int E) {
    int i = blockIdx.x * blockDim.x + threadIdx.x;
    if (i < E) {
        int d = dst[i];
        int p = atomicAdd(&cursor[d], 1);
        edge_src[p] = src[i];
    }
}

// S = X@Wself + b ; P = X@Wneigh.  X: M x K row-major, W: K x 64 row-major.
// block = 256 threads, tile = 64 rows x 64 cols, each thread 4 rows x 4 cols x 2 mats.
template <int K>
__global__ __launch_bounds__(256) void gemm_dual_kernel(
    const float* __restrict__ X, const float* __restrict__ Ws_g,
    const float* __restrict__ Wn_g, const float* __restrict__ bias,
    float* __restrict__ S, float* __restrict__ P, int M) {
    __shared__ float Xs[64][68];   // stride 68: 16B-aligned float4 rows, banks ok
    __shared__ float Ws[64][68];
    __shared__ float Wn[64][68];
    int tid = threadIdx.x;
    int row0 = blockIdx.x * 64;
    int cx = tid & 15;    // col group: cols cx + 16*i
    int ry = tid >> 4;    // row group: rows 4*ry + j
    float acc_s[4][4] = {{0.f}};
    float acc_n[4][4] = {{0.f}};

    for (int kc = 0; kc < K; kc += 64) {
#pragma unroll
        for (int it = 0; it < 4; ++it) {
            int q = tid + 256 * it;       // 0..1023
            int row = q >> 4;             // 0..63
            int k4 = (q & 15) * 4;        // 0..60
            float4 xv;
            int gr = row0 + row;
            if (gr < M)
                xv = *reinterpret_cast<const float4*>(&X[(size_t)gr * K + kc + k4]);
            else
                xv = make_float4(0.f, 0.f, 0.f, 0.f);
            *reinterpret_cast<float4*>(&Xs[row][k4]) = xv;
            float4 wv = *reinterpret_cast<const float4*>(&Ws_g[(size_t)(kc + row) * 64 + k4]);
            *reinterpret_cast<float4*>(&Ws[row][k4]) = wv;
            float4 nv = *reinterpret_cast<const float4*>(&Wn_g[(size_t)(kc + row) * 64 + k4]);
            *reinterpret_cast<float4*>(&Wn[row][k4]) = nv;
        }
        __syncthreads();
#pragma unroll 4
        for (int kk = 0; kk < 64; ++kk) {
            float a[4], bs[4], bn[4];
#pragma unroll
            for (int j = 0; j < 4; ++j) a[j] = Xs[ry * 4 + j][kk];
#pragma unroll
            for (int i = 0; i < 4; ++i) {
                bs[i] = Ws[kk][cx + 16 * i];
                bn[i] = Wn[kk][cx + 16 * i];
            }
#pragma unroll
            for (int j = 0; j < 4; ++j)
#pragma unroll
                for (int i = 0; i < 4; ++i) {
                    acc_s[j][i] += a[j] * bs[i];
                    acc_n[j][i] += a[j] * bn[i];
                }
        }
        __syncthreads();
    }

#pragma unroll
    for (int j = 0; j < 4; ++j) {
        int r = row0 + ry * 4 + j;
        if (r < M) {
#pragma unroll
            for (int i = 0; i < 4; ++i) {
                int c = cx + 16 * i;
                S[(size_t)r * DH + c] = acc_s[j][i] + bias[c];
                P[(size_t)r * DH + c] = acc_n[j][i];
            }
        }
    }
}

// one wave (64 lanes) per node. Wave = 4 edge-groups (g) x 16 lanes (t);
// lane loads float4 of one P row -> one load instr gathers 4 rows (1 KB).
// Index loads are software-pipelined one macro-iteration ahead.
template <bool RELU, bool READOUT>
__global__ __launch_bounds__(256) void agg_kernel(
    const float* __restrict__ S, const float* __restrict__ P,
    const int* __restrict__ row_start, const int* __restrict__ edge_src,
    float* __restrict__ H, const int* __restrict__ graph_id,
    float* __restrict__ gsum, float* __restrict__ gcnt, int M) {
    int tid = threadIdx.x;
    int lane = tid & 63;
    int n = blockIdx.x * 4 + (tid >> 6);
    if (n >= M) return;
    int g = lane >> 4;    // edge slot within batch of 4
    int t = lane & 15;    // float4 chunk of the 64-dim row

    int e0 = row_start[n], e1 = row_start[n + 1];
    int deg = e1 - e0;
    float ax = 0.f, ay = 0.f, az = 0.f, aw = 0.f;

    int e = e0;
    int i0 = 0, i1 = 0;
    bool have = (e + 8 <= e1);
    if (have) { i0 = edge_src[e + g]; i1 = edge_src[e + 4 + g]; }
    while (have) {
        const float4 a = *reinterpret_cast<const float4*>(&P[(size_t)i0 * DH + t * 4]);
        const float4 b = *reinterpret_cast<const float4*>(&P[(size_t)i1 * DH + t * 4]);
        e += 8;
        have = (e + 8 <= e1);
        if (have) { i0 = edge_src[e + g]; i1 = edge_src[e + 4 + g]; }  // prefetch next
        ax += a.x; ay += a.y; az += a.z; aw += a.w;
        ax += b.x; ay += b.y; az += b.z; aw += b.w;
    }
    if (e + 4 <= e1) {
        int i = edge_src[e + g];
        const float4 a = *reinterpret_cast<const float4*>(&P[(size_t)i * DH + t * 4]);
        ax += a.x; ay += a.y; az += a.z; aw += a.w;
        e += 4;
    }
    if (e < e1 && g < (e1 - e)) {   // 1-3 leftover edges: groups 0..rem-1 take one each
        int i = edge_src[e + g];
        const float4 a = *reinterpret_cast<const float4*>(&P[(size_t)i * DH + t * 4]);
        ax += a.x; ay += a.y; az += a.z; aw += a.w;
    }

    // reduce across the 4 edge-groups (lanes t, t+16, t+32, t+48)
#pragma unroll
    for (int m = 16; m <= 32; m <<= 1) {
        ax += __shfl_xor(ax, m, 64);
        ay += __shfl_xor(ay, m, 64);
        az += __shfl_xor(az, m, 64);
        aw += __shfl_xor(aw, m, 64);
    }

    if (g == 0) {
        float inv = 1.0f / fmaxf((float)deg, 1.0f);
        const float4 s = *reinterpret_cast<const float4*>(&S[(size_t)n * DH + t * 4]);
        float4 val;
        val.x = s.x + ax * inv;
        val.y = s.y + ay * inv;
        val.z = s.z + az * inv;
        val.w = s.w + aw * inv;
        if (RELU) {
            val.x = fmaxf(val.x, 0.f); val.y = fmaxf(val.y, 0.f);
            val.z = fmaxf(val.z, 0.f); val.w = fmaxf(val.w, 0.f);
        }
        *reinterpret_cast<float4*>(&H[(size_t)n * DH + t * 4]) = val;
        if (READOUT) {
            int gid = graph_id[n];
            atomicAdd(&gsum[gid * DH + t * 4 + 0], val.x);
            atomicAdd(&gsum[gid * DH + t * 4 + 1], val.y);
            atomicAdd(&gsum[gid * DH + t * 4 + 2], val.z);
            atomicAdd(&gsum[gid * DH + t * 4 + 3], val.w);
            if (t == 0) atomicAdd(&gcnt[gid], 1.0f);
        }
    }
}

// single block of 1024: out_feat = gsum/cnt ; out = out_feat @ W_cls + b_cls
__global__ __launch_bounds__(1024) void readout_kernel(
    const float* __restrict__ gsum, const float* __restrict__ gcnt,
    const float* __restrict__ Wc, const float* __restrict__ bc,
    float* __restrict__ out, float* __restrict__ out_feat) {
    __shared__ float ofs[NG][DH];
    int tid = threadIdx.x;
    int g = tid >> 6, d = tid & 63;
    float of = gsum[tid] / fmaxf(gcnt[g], 1.0f);
    out_feat[tid] = of;
    ofs[g][d] = of;
    __syncthreads();
    if (tid < NG * 2) {
        int gg = tid >> 1, cc = tid & 1;
        float acc = bc[cc];
#pragma unroll 8
        for (int dd = 0; dd < DH; ++dd) acc += ofs[gg][dd] * Wc[dd * 2 + cc];
        out[gg * 2 + cc] = acc;
    }
}

extern "C" void kernel_launch(void* const* d_in, const int* in_sizes, int n_in,
                              void* d_out, int out_size, void* d_ws, size_t ws_size,
                              hipStream_t stream) {
    const float* feat     = (const float*)d_in[0];
    const int*   src      = (const int*)d_in[1];
    const int*   dst      = (const int*)d_in[2];
    const int*   graph_id = (const int*)d_in[3];
    const float* Ws1 = (const float*)d_in[4];
    const float* Wn1 = (const float*)d_in[5];
    const float* b1  = (const float*)d_in[6];
    const float* Ws2 = (const float*)d_in[7];
    const float* Wn2 = (const float*)d_in[8];
    const float* b2  = (const float*)d_in[9];
    const float* Ws3 = (const float*)d_in[10];
    const float* Wn3 = (const float*)d_in[11];
    const float* b3  = (const float*)d_in[12];
    const float* Wc  = (const float*)d_in[13];
    const float* bc  = (const float*)d_in[14];

    const int M = in_sizes[3];   // 10000 nodes
    const int E = in_sizes[1];   // 320000 edges

    float* out      = (float*)d_out;             // 16 x 2
    float* out_feat = out + NG * 2;              // 16 x 64
    float* Hbuf     = out_feat + NG * DH;        // 10000 x 64 (final h; also reused per layer)

    // workspace layout
    char* w = (char*)d_ws;
    size_t off = 0;
    auto carve = [&](size_t bytes) {
        size_t o = off;
        off = (off + bytes + 15) & ~(size_t)15;
        return o;
    };
    int*   deg      = (int*)  (w + carve((size_t)M * 4));
    float* gsum     = (float*)(w + carve((size_t)NG * DH * 4));
    float* gcnt     = (float*)(w + carve((size_t)NG * 4));
    size_t zero_bytes = off;                       // deg + gsum + gcnt
    int*   row_start = (int*)  (w + carve((size_t)(M + 1) * 4));
    int*   cursor    = (int*)  (w + carve((size_t)M * 4));
    int*   edge_src  = (int*)  (w + carve((size_t)E * 4));
    float* Sbuf      = (float*)(w + carve((size_t)M * DH * 4));
    float* Pbuf      = (float*)(w + carve((size_t)M * DH * 4));
    (void)ws_size; (void)n_in; (void)out_size;

    hipMemsetAsync(d_ws, 0, zero_bytes, stream);

    int eb = (E + 255) / 256;
    deg_count_kernel<<<eb, 256, 0, stream>>>(dst, deg, E);
    scan_kernel<<<1, 1024, 0, stream>>>(deg, row_start, cursor, M);
    scatter_kernel<<<eb, 256, 0, stream>>>(src, dst, cursor, edge_src, E);

    int gb = (M + 63) / 64;   // gemm blocks
    int ab = (M + 3) / 4;     // agg blocks

    // layer 1 (K=256), relu
    gemm_dual_kernel<256><<<gb, 256, 0, stream>>>(feat, Ws1, Wn1, b1, Sbuf, Pbuf, M);
    agg_kernel<true, false><<<ab, 256, 0, stream>>>(Sbuf, Pbuf, row_start, edge_src,
                                                    Hbuf, graph_id, gsum, gcnt, M);
    // layer 2 (K=64), relu
    gemm_dual_kernel<64><<<gb, 256, 0, stream>>>(Hbuf, Ws2, Wn2, b2, Sbuf, Pbuf, M);
    agg_kernel<true, false><<<ab, 256, 0, stream>>>(Sbuf, Pbuf, row_start, edge_src,
                                                    Hbuf, graph_id, gsum, gcnt, M);
    // layer 3 (K=64), no relu, fused readout accumulation
    gemm_dual_kernel<64><<<gb, 256, 0, stream>>>(Hbuf, Ws3, Wn3, b3, Sbuf, Pbuf, M);
    agg_kernel<false, true><<<ab, 256, 0, stream>>>(Sbuf, Pbuf, row_start, edge_src,
                                                    Hbuf, graph_id, gsum, gcnt, M);

    readout_kernel<<<1, 1024, 0, stream>>>(gsum, gcnt, Wc, bc, out, out_feat);
}

// Round 6
// 363.952 us; speedup vs baseline: 1.0114x; 1.0114x over previous
//
#include <hip/hip_runtime.h>

// ---------------------------------------------------------------------------
// SAGE 3-layer GNN, fp32.
//   Per layer: S = X@W_self + b ; P = X@W_neigh  (one dual GEMM kernel)
//              h[i] = act( S[i] + (sum_{j in N_in(i)} P[j]) / max(deg_i,1) )
//   CSR built once, reused 3 layers. Readout fused into layer-3 agg.
//
// R1 FAILED perf: index-prefetch depth 1 drains vmcnt(0) per iteration.
// R3/R4 FAILED correctness (~0.35 on h): __shfl-based index distribution —
//   partition audited correct on paper; treating divergent-srcLane __shfl
//   as hazardous and reverting to the R2-PASSED direct-load index path.
// R5: masked batch-of-32 inner loop with DIRECT index loads (edge_src[e+4k+g],
//   proven in R2): 8 independent idx loads in flight, then 8 independent
//   float4 row loads in flight (8KB/wave). Out-of-range slots clamp to a
//   valid address and are zero-weighted via fmaf -> no tail tiers, ~2
//   latency round-trips per node instead of ~8-16.
// ---------------------------------------------------------------------------

#define DH 64
#define NG 16

__global__ void deg_count_kernel(const int* __restrict__ dst, int* __restrict__ deg, int E) {
    int i = blockIdx.x * blockDim.x + threadIdx.x;
    if (i < E) atomicAdd(&deg[dst[i]], 1);
}

// single-block exclusive prefix scan over deg -> row_start (and cursor copy)
// (R0/R2-passed version)
__global__ void scan_kernel(const int* __restrict__ deg, int* __restrict__ row_start,
                            int* __restrict__ cursor, int M) {
    __shared__ int sdata[1024];
    __shared__ int s_base;
    int tid = threadIdx.x;
    if (tid == 0) s_base = 0;
    __syncthreads();
    for (int base = 0; base < M; base += 1024) {
        int v = (base + tid < M) ? deg[base + tid] : 0;
        sdata[tid] = v;
        __syncthreads();
        for (int off = 1; off < 1024; off <<= 1) {
            int t = (tid >= off) ? sdata[tid - off] : 0;
            __syncthreads();
            sdata[tid] += t;
            __syncthreads();
        }
        int excl = sdata[tid] - v;
        if (base + tid < M) {
            int rs = s_base + excl;
            row_start[base + tid] = rs;
            cursor[base + tid] = rs;
        }
        __syncthreads();
        if (tid == 1023) s_base += sdata[1023];
        __syncthreads();
    }
    if (tid == 0) row_start[M] = s_base;
}

__global__ void scatter_kernel(const int* __restrict__ src, const int* __restrict__ dst,
                               int* __restrict__ cursor, int* __restrict__ edge_src, int E) {
    int i = blockIdx.x * blockDim.x + threadIdx.x;
    if (i < E) {
        int d = dst[i];
        int p = atomicAdd(&cursor[d], 1);
        edge_src[p] = src[i];
    }
}

// S = X@Wself + b ; P = X@Wneigh.  X: M x K row-major, W: K x 64 row-major.
// (R2-passed version: thread owns 4 rows x 4 strided cols per matrix)
template <int K>
__global__ __launch_bounds__(256) void gemm_dual_kernel(
    const float* __restrict__ X, const float* __restrict__ Ws_g,
    const float* __restrict__ Wn_g, const float* __restrict__ bias,
    float* __restrict__ S, float* __restrict__ P, int M) {
    __shared__ float Xs[64][68];   // stride 68: 16B-aligned float4 rows
    __shared__ float Ws[64][68];
    __shared__ float Wn[64][68];
    int tid = threadIdx.x;
    int row0 = blockIdx.x * 64;
    int cx = tid & 15;    // col group: cols cx + 16*i
    int ry = tid >> 4;    // row group: rows 4*ry + j
    float acc_s[4][4] = {{0.f}};
    float acc_n[4][4] = {{0.f}};

    for (int kc = 0; kc < K; kc += 64) {
#pragma unroll
        for (int it = 0; it < 4; ++it) {
            int q = tid + 256 * it;       // 0..1023
            int row = q >> 4;             // 0..63
            int k4 = (q & 15) * 4;        // 0..60
            float4 xv;
            int gr = row0 + row;
            if (gr < M)
                xv = *reinterpret_cast<const float4*>(&X[(size_t)gr * K + kc + k4]);
            else
                xv = make_float4(0.f, 0.f, 0.f, 0.f);
            *reinterpret_cast<float4*>(&Xs[row][k4]) = xv;
            float4 wv = *reinterpret_cast<const float4*>(&Ws_g[(size_t)(kc + row) * 64 + k4]);
            *reinterpret_cast<float4*>(&Ws[row][k4]) = wv;
            float4 nv = *reinterpret_cast<const float4*>(&Wn_g[(size_t)(kc + row) * 64 + k4]);
            *reinterpret_cast<float4*>(&Wn[row][k4]) = nv;
        }
        __syncthreads();
#pragma unroll 4
        for (int kk = 0; kk < 64; ++kk) {
            float a[4], bs[4], bn[4];
#pragma unroll
            for (int j = 0; j < 4; ++j) a[j] = Xs[ry * 4 + j][kk];
#pragma unroll
            for (int i = 0; i < 4; ++i) {
                bs[i] = Ws[kk][cx + 16 * i];
                bn[i] = Wn[kk][cx + 16 * i];
            }
#pragma unroll
            for (int j = 0; j < 4; ++j)
#pragma unroll
                for (int i = 0; i < 4; ++i) {
                    acc_s[j][i] += a[j] * bs[i];
                    acc_n[j][i] += a[j] * bn[i];
                }
        }
        __syncthreads();
    }

#pragma unroll
    for (int j = 0; j < 4; ++j) {
        int r = row0 + ry * 4 + j;
        if (r < M) {
#pragma unroll
            for (int i = 0; i < 4; ++i) {
                int c = cx + 16 * i;
                S[(size_t)r * DH + c] = acc_s[j][i] + bias[c];
                P[(size_t)r * DH + c] = acc_n[j][i];
            }
        }
    }
}

// one wave per node; wave = 4 edge-groups (g) x 16 lanes (t), float4 per lane.
// Masked batch of 32 edges per iteration: 8 direct idx loads in flight, then
// 8 float4 row loads in flight; out-of-range slots clamp addr + 0-weight fma.
template <bool RELU, bool READOUT>
__global__ __launch_bounds__(256) void agg_kernel(
    const float* __restrict__ S, const float* __restrict__ P,
    const int* __restrict__ row_start, const int* __restrict__ edge_src,
    float* __restrict__ H, const int* __restrict__ graph_id,
    float* __restrict__ gsum, float* __restrict__ gcnt, int M) {
    int tid = threadIdx.x;
    int lane = tid & 63;
    int n = blockIdx.x * 4 + (tid >> 6);
    if (n >= M) return;
    int g = lane >> 4;    // edge group: slot covers edges e+4k+g
    int t = lane & 15;    // float4 chunk of row

    int e0 = row_start[n], e1 = row_start[n + 1];
    int deg = e1 - e0;

    float ax = 0.f, ay = 0.f, az = 0.f, aw = 0.f;
    for (int e = e0; e < e1; e += 32) {
        int c = e1 - 1;   // valid clamp target (loop body implies e1 >= 1)
        int q0 = e + g,      q1 = e + 4 + g,  q2 = e + 8 + g,  q3 = e + 12 + g;
        int q4 = e + 16 + g, q5 = e + 20 + g, q6 = e + 24 + g, q7 = e + 28 + g;
        // 8 independent index loads (addresses independent of any load)
        int i0 = edge_src[min(q0, c)];
        int i1 = edge_src[min(q1, c)];
        int i2 = edge_src[min(q2, c)];
        int i3 = edge_src[min(q3, c)];
        int i4 = edge_src[min(q4, c)];
        int i5 = edge_src[min(q5, c)];
        int i6 = edge_src[min(q6, c)];
        int i7 = edge_src[min(q7, c)];
        float m0 = (q0 < e1) ? 1.f : 0.f;
        float m1 = (q1 < e1) ? 1.f : 0.f;
        float m2 = (q2 < e1) ? 1.f : 0.f;
        float m3 = (q3 < e1) ? 1.f : 0.f;
        float m4 = (q4 < e1) ? 1.f : 0.f;
        float m5 = (q5 < e1) ? 1.f : 0.f;
        float m6 = (q6 < e1) ? 1.f : 0.f;
        float m7 = (q7 < e1) ? 1.f : 0.f;
        // 8 independent row loads (8KB per wave in flight)
        float4 a0 = *reinterpret_cast<const float4*>(&P[(size_t)i0 * DH + t * 4]);
        float4 a1 = *reinterpret_cast<const float4*>(&P[(size_t)i1 * DH + t * 4]);
        float4 a2 = *reinterpret_cast<const float4*>(&P[(size_t)i2 * DH + t * 4]);
        float4 a3 = *reinterpret_cast<const float4*>(&P[(size_t)i3 * DH + t * 4]);
        float4 a4 = *reinterpret_cast<const float4*>(&P[(size_t)i4 * DH + t * 4]);
        float4 a5 = *reinterpret_cast<const float4*>(&P[(size_t)i5 * DH + t * 4]);
        float4 a6 = *reinterpret_cast<const float4*>(&P[(size_t)i6 * DH + t * 4]);
        float4 a7 = *reinterpret_cast<const float4*>(&P[(size_t)i7 * DH + t * 4]);
        ax = fmaf(m0, a0.x, ax); ay = fmaf(m0, a0.y, ay); az = fmaf(m0, a0.z, az); aw = fmaf(m0, a0.w, aw);
        ax = fmaf(m1, a1.x, ax); ay = fmaf(m1, a1.y, ay); az = fmaf(m1, a1.z, az); aw = fmaf(m1, a1.w, aw);
        ax = fmaf(m2, a2.x, ax); ay = fmaf(m2, a2.y, ay); az = fmaf(m2, a2.z, az); aw = fmaf(m2, a2.w, aw);
        ax = fmaf(m3, a3.x, ax); ay = fmaf(m3, a3.y, ay); az = fmaf(m3, a3.z, az); aw = fmaf(m3, a3.w, aw);
        ax = fmaf(m4, a4.x, ax); ay = fmaf(m4, a4.y, ay); az = fmaf(m4, a4.z, az); aw = fmaf(m4, a4.w, aw);
        ax = fmaf(m5, a5.x, ax); ay = fmaf(m5, a5.y, ay); az = fmaf(m5, a5.z, az); aw = fmaf(m5, a5.w, aw);
        ax = fmaf(m6, a6.x, ax); ay = fmaf(m6, a6.y, ay); az = fmaf(m6, a6.z, az); aw = fmaf(m6, a6.w, aw);
        ax = fmaf(m7, a7.x, ax); ay = fmaf(m7, a7.y, ay); az = fmaf(m7, a7.z, az); aw = fmaf(m7, a7.w, aw);
    }

    // reduce across the 4 edge-groups (lanes t, t+16, t+32, t+48)
#pragma unroll
    for (int m = 16; m <= 32; m <<= 1) {
        ax += __shfl_xor(ax, m, 64);
        ay += __shfl_xor(ay, m, 64);
        az += __shfl_xor(az, m, 64);
        aw += __shfl_xor(aw, m, 64);
    }

    if (g == 0) {
        float inv = 1.0f / fmaxf((float)deg, 1.0f);
        const float4 s = *reinterpret_cast<const float4*>(&S[(size_t)n * DH + t * 4]);
        float4 val;
        val.x = s.x + ax * inv;
        val.y = s.y + ay * inv;
        val.z = s.z + az * inv;
        val.w = s.w + aw * inv;
        if (RELU) {
            val.x = fmaxf(val.x, 0.f); val.y = fmaxf(val.y, 0.f);
            val.z = fmaxf(val.z, 0.f); val.w = fmaxf(val.w, 0.f);
        }
        *reinterpret_cast<float4*>(&H[(size_t)n * DH + t * 4]) = val;
        if (READOUT) {
            int gid = graph_id[n];
            atomicAdd(&gsum[gid * DH + t * 4 + 0], val.x);
            atomicAdd(&gsum[gid * DH + t * 4 + 1], val.y);
            atomicAdd(&gsum[gid * DH + t * 4 + 2], val.z);
            atomicAdd(&gsum[gid * DH + t * 4 + 3], val.w);
            if (t == 0) atomicAdd(&gcnt[gid], 1.0f);
        }
    }
}

// single block of 1024: out_feat = gsum/cnt ; out = out_feat @ W_cls + b_cls
__global__ __launch_bounds__(1024) void readout_kernel(
    const float* __restrict__ gsum, const float* __restrict__ gcnt,
    const float* __restrict__ Wc, const float* __restrict__ bc,
    float* __restrict__ out, float* __restrict__ out_feat) {
    __shared__ float ofs[NG][DH];
    int tid = threadIdx.x;
    int g = tid >> 6, d = tid & 63;
    float of = gsum[tid] / fmaxf(gcnt[g], 1.0f);
    out_feat[tid] = of;
    ofs[g][d] = of;
    __syncthreads();
    if (tid < NG * 2) {
        int gg = tid >> 1, cc = tid & 1;
        float acc = bc[cc];
#pragma unroll 8
        for (int dd = 0; dd < DH; ++dd) acc += ofs[gg][dd] * Wc[dd * 2 + cc];
        out[gg * 2 + cc] = acc;
    }
}

extern "C" void kernel_launch(void* const* d_in, const int* in_sizes, int n_in,
                              void* d_out, int out_size, void* d_ws, size_t ws_size,
                              hipStream_t stream) {
    const float* feat     = (const float*)d_in[0];
    const int*   src      = (const int*)d_in[1];
    const int*   dst      = (const int*)d_in[2];
    const int*   graph_id = (const int*)d_in[3];
    const float* Ws1 = (const float*)d_in[4];
    const float* Wn1 = (const float*)d_in[5];
    const float* b1  = (const float*)d_in[6];
    const float* Ws2 = (const float*)d_in[7];
    const float* Wn2 = (const float*)d_in[8];
    const float* b2  = (const float*)d_in[9];
    const float* Ws3 = (const float*)d_in[10];
    const float* Wn3 = (const float*)d_in[11];
    const float* b3  = (const float*)d_in[12];
    const float* Wc  = (const float*)d_in[13];
    const float* bc  = (const float*)d_in[14];

    const int M = in_sizes[3];   // 10000 nodes
    const int E = in_sizes[1];   // 320000 edges

    float* out      = (float*)d_out;             // 16 x 2
    float* out_feat = out + NG * 2;              // 16 x 64
    float* Hbuf     = out_feat + NG * DH;        // 10000 x 64 (final h)

    // workspace layout
    char* w = (char*)d_ws;
    size_t off = 0;
    auto carve = [&](size_t bytes) {
        size_t o = off;
        off = (off + bytes + 15) & ~(size_t)15;
        return o;
    };
    int*   deg      = (int*)  (w + carve((size_t)M * 4));
    float* gsum     = (float*)(w + carve((size_t)NG * DH * 4));
    float* gcnt     = (float*)(w + carve((size_t)NG * 4));
    size_t zero_bytes = off;                       // deg + gsum + gcnt
    int*   row_start = (int*)  (w + carve((size_t)(M + 1) * 4));
    int*   cursor    = (int*)  (w + carve((size_t)M * 4));
    int*   edge_src  = (int*)  (w + carve((size_t)E * 4));
    float* Sbuf      = (float*)(w + carve((size_t)M * DH * 4));
    float* Pbuf      = (float*)(w + carve((size_t)M * DH * 4));
    (void)ws_size; (void)n_in; (void)out_size;

    (void)hipMemsetAsync(d_ws, 0, zero_bytes, stream);

    int eb = (E + 255) / 256;
    deg_count_kernel<<<eb, 256, 0, stream>>>(dst, deg, E);
    scan_kernel<<<1, 1024, 0, stream>>>(deg, row_start, cursor, M);
    scatter_kernel<<<eb, 256, 0, stream>>>(src, dst, cursor, edge_src, E);

    int gb = (M + 63) / 64;   // gemm blocks
    int ab = (M + 3) / 4;     // agg blocks

    // layer 1 (K=256), relu
    gemm_dual_kernel<256><<<gb, 256, 0, stream>>>(feat, Ws1, Wn1, b1, Sbuf, Pbuf, M);
    agg_kernel<true, false><<<ab, 256, 0, stream>>>(Sbuf, Pbuf, row_start, edge_src,
                                                    Hbuf, graph_id, gsum, gcnt, M);
    // layer 2 (K=64), relu
    gemm_dual_kernel<64><<<gb, 256, 0, stream>>>(Hbuf, Ws2, Wn2, b2, Sbuf, Pbuf, M);
    agg_kernel<true, false><<<ab, 256, 0, stream>>>(Sbuf, Pbuf, row_start, edge_src,
                                                    Hbuf, graph_id, gsum, gcnt, M);
    // layer 3 (K=64), no relu, fused readout accumulation
    gemm_dual_kernel<64><<<gb, 256, 0, stream>>>(Hbuf, Ws3, Wn3, b3, Sbuf, Pbuf, M);
    agg_kernel<false, true><<<ab, 256, 0, stream>>>(Sbuf, Pbuf, row_start, edge_src,
                                                    Hbuf, graph_id, gsum, gcnt, M);

    readout_kernel<<<1, 1024, 0, stream>>>(gsum, gcnt, Wc, bc, out, out_feat);
}

// Round 7
// 361.976 us; speedup vs baseline: 1.0169x; 1.0055x over previous
//
#include <hip/hip_runtime.h>

// ---------------------------------------------------------------------------
// SAGE 3-layer GNN.
//   Per layer: S = X@W_self + b (fp32) ; P = X@W_neigh (stored BF16)
//              h[i] = act( S[i] + (sum_{j in N_in(i)} P[j]) / max(deg_i,1) )
//   CSR built once, reused 3 layers. Readout fused into layer-3 agg.
//
// Evidence log:
//   R0/R1/R5 agg all ~135-143us profiled despite totally different inner
//   loops (serial scalar / prefetch-1 / straight-line 8-in-flight).
//   VALUBusy ~2%, HBM ~2%, conflicts 0, occ ~45% -> the wall is the per-CU
//   random-row-gather service rate (~274 cyc/edge/CU ~ 1 B/cyc/CU).
// R7 experiment: P stored in BF16 -> row 256B -> 128B. If gather cost is
//   per-byte, agg halves; if per-row latency, neutral -> pivot to reuse.
//   S/H stay fp32 (self term exact); only neighbor messages are bf16.
// ---------------------------------------------------------------------------

#define DH 64
#define NG 16

__device__ __forceinline__ unsigned short f2bf(float f) {
    unsigned int u = __float_as_uint(f);
    unsigned int r = (u + 0x7FFFu + ((u >> 16) & 1u)) >> 16;   // RNE
    return (unsigned short)r;
}
__device__ __forceinline__ float bflo(unsigned int u) { return __uint_as_float(u << 16); }
__device__ __forceinline__ float bfhi(unsigned int u) { return __uint_as_float(u & 0xFFFF0000u); }

__global__ void deg_count_kernel(const int* __restrict__ dst, int* __restrict__ deg, int E) {
    int i = blockIdx.x * blockDim.x + threadIdx.x;
    if (i < E) atomicAdd(&deg[dst[i]], 1);
}

// single-block exclusive prefix scan over deg -> row_start (and cursor copy)
__global__ void scan_kernel(const int* __restrict__ deg, int* __restrict__ row_start,
                            int* __restrict__ cursor, int M) {
    __shared__ int sdata[1024];
    __shared__ int s_base;
    int tid = threadIdx.x;
    if (tid == 0) s_base = 0;
    __syncthreads();
    for (int base = 0; base < M; base += 1024) {
        int v = (base + tid < M) ? deg[base + tid] : 0;
        sdata[tid] = v;
        __syncthreads();
        for (int off = 1; off < 1024; off <<= 1) {
            int t = (tid >= off) ? sdata[tid - off] : 0;
            __syncthreads();
            sdata[tid] += t;
            __syncthreads();
        }
        int excl = sdata[tid] - v;
        if (base + tid < M) {
            int rs = s_base + excl;
            row_start[base + tid] = rs;
            cursor[base + tid] = rs;
        }
        __syncthreads();
        if (tid == 1023) s_base += sdata[1023];
        __syncthreads();
    }
    if (tid == 0) row_start[M] = s_base;
}

__global__ void scatter_kernel(const int* __restrict__ src, const int* __restrict__ dst,
                               int* __restrict__ cursor, int* __restrict__ edge_src, int E) {
    int i = blockIdx.x * blockDim.x + threadIdx.x;
    if (i < E) {
        int d = dst[i];
        int p = atomicAdd(&cursor[d], 1);
        edge_src[p] = src[i];
    }
}

// S = X@Wself + b (fp32) ; P = X@Wneigh (bf16).  X: MxK row-major, W: Kx64.
template <int K>
__global__ __launch_bounds__(256) void gemm_dual_kernel(
    const float* __restrict__ X, const float* __restrict__ Ws_g,
    const float* __restrict__ Wn_g, const float* __restrict__ bias,
    float* __restrict__ S, unsigned short* __restrict__ P, int M) {
    __shared__ float Xs[64][68];   // stride 68: 16B-aligned float4 rows
    __shared__ float Ws[64][68];
    __shared__ float Wn[64][68];
    int tid = threadIdx.x;
    int row0 = blockIdx.x * 64;
    int cx = tid & 15;    // col group: cols cx + 16*i
    int ry = tid >> 4;    // row group: rows 4*ry + j
    float acc_s[4][4] = {{0.f}};
    float acc_n[4][4] = {{0.f}};

    for (int kc = 0; kc < K; kc += 64) {
#pragma unroll
        for (int it = 0; it < 4; ++it) {
            int q = tid + 256 * it;       // 0..1023
            int row = q >> 4;             // 0..63
            int k4 = (q & 15) * 4;        // 0..60
            float4 xv;
            int gr = row0 + row;
            if (gr < M)
                xv = *reinterpret_cast<const float4*>(&X[(size_t)gr * K + kc + k4]);
            else
                xv = make_float4(0.f, 0.f, 0.f, 0.f);
            *reinterpret_cast<float4*>(&Xs[row][k4]) = xv;
            float4 wv = *reinterpret_cast<const float4*>(&Ws_g[(size_t)(kc + row) * 64 + k4]);
            *reinterpret_cast<float4*>(&Ws[row][k4]) = wv;
            float4 nv = *reinterpret_cast<const float4*>(&Wn_g[(size_t)(kc + row) * 64 + k4]);
            *reinterpret_cast<float4*>(&Wn[row][k4]) = nv;
        }
        __syncthreads();
#pragma unroll 4
        for (int kk = 0; kk < 64; ++kk) {
            float a[4], bs[4], bn[4];
#pragma unroll
            for (int j = 0; j < 4; ++j) a[j] = Xs[ry * 4 + j][kk];
#pragma unroll
            for (int i = 0; i < 4; ++i) {
                bs[i] = Ws[kk][cx + 16 * i];
                bn[i] = Wn[kk][cx + 16 * i];
            }
#pragma unroll
            for (int j = 0; j < 4; ++j)
#pragma unroll
                for (int i = 0; i < 4; ++i) {
                    acc_s[j][i] += a[j] * bs[i];
                    acc_n[j][i] += a[j] * bn[i];
                }
        }
        __syncthreads();
    }

#pragma unroll
    for (int j = 0; j < 4; ++j) {
        int r = row0 + ry * 4 + j;
        if (r < M) {
#pragma unroll
            for (int i = 0; i < 4; ++i) {
                int c = cx + 16 * i;
                S[(size_t)r * DH + c] = acc_s[j][i] + bias[c];
                P[(size_t)r * DH + c] = f2bf(acc_n[j][i]);
            }
        }
    }
}

// one wave per node; wave = 4 edge-groups (g) x 16 lanes (t).
// P rows are bf16 (128 B): lane t loads uint2 = 4 bf16 dims.
// Masked batch of 32 edges/iter: 8 idx loads in flight, then 8 row loads.
template <bool RELU, bool READOUT>
__global__ __launch_bounds__(256) void agg_kernel(
    const float* __restrict__ S, const unsigned short* __restrict__ P,
    const int* __restrict__ row_start, const int* __restrict__ edge_src,
    float* __restrict__ H, const int* __restrict__ graph_id,
    float* __restrict__ gsum, float* __restrict__ gcnt, int M) {
    int tid = threadIdx.x;
    int lane = tid & 63;
    int n = blockIdx.x * 4 + (tid >> 6);
    if (n >= M) return;
    int g = lane >> 4;    // edge group: slot covers edges e+4k+g
    int t = lane & 15;    // 4-dim chunk of row

    int e0 = row_start[n], e1 = row_start[n + 1];
    int deg = e1 - e0;

    float ax = 0.f, ay = 0.f, az = 0.f, aw = 0.f;
    for (int e = e0; e < e1; e += 32) {
        int c = e1 - 1;   // valid clamp target (loop body implies e1 >= 1)
        int q0 = e + g,      q1 = e + 4 + g,  q2 = e + 8 + g,  q3 = e + 12 + g;
        int q4 = e + 16 + g, q5 = e + 20 + g, q6 = e + 24 + g, q7 = e + 28 + g;
        int i0 = edge_src[min(q0, c)];
        int i1 = edge_src[min(q1, c)];
        int i2 = edge_src[min(q2, c)];
        int i3 = edge_src[min(q3, c)];
        int i4 = edge_src[min(q4, c)];
        int i5 = edge_src[min(q5, c)];
        int i6 = edge_src[min(q6, c)];
        int i7 = edge_src[min(q7, c)];
        float m0 = (q0 < e1) ? 1.f : 0.f;
        float m1 = (q1 < e1) ? 1.f : 0.f;
        float m2 = (q2 < e1) ? 1.f : 0.f;
        float m3 = (q3 < e1) ? 1.f : 0.f;
        float m4 = (q4 < e1) ? 1.f : 0.f;
        float m5 = (q5 < e1) ? 1.f : 0.f;
        float m6 = (q6 < e1) ? 1.f : 0.f;
        float m7 = (q7 < e1) ? 1.f : 0.f;
        // 8 independent bf16 row loads (8 B/lane, 512 B/wave each)
        uint2 a0 = *reinterpret_cast<const uint2*>(&P[((size_t)i0 << 6) + t * 4]);
        uint2 a1 = *reinterpret_cast<const uint2*>(&P[((size_t)i1 << 6) + t * 4]);
        uint2 a2 = *reinterpret_cast<const uint2*>(&P[((size_t)i2 << 6) + t * 4]);
        uint2 a3 = *reinterpret_cast<const uint2*>(&P[((size_t)i3 << 6) + t * 4]);
        uint2 a4 = *reinterpret_cast<const uint2*>(&P[((size_t)i4 << 6) + t * 4]);
        uint2 a5 = *reinterpret_cast<const uint2*>(&P[((size_t)i5 << 6) + t * 4]);
        uint2 a6 = *reinterpret_cast<const uint2*>(&P[((size_t)i6 << 6) + t * 4]);
        uint2 a7 = *reinterpret_cast<const uint2*>(&P[((size_t)i7 << 6) + t * 4]);
        ax = fmaf(m0, bflo(a0.x), ax); ay = fmaf(m0, bfhi(a0.x), ay);
        az = fmaf(m0, bflo(a0.y), az); aw = fmaf(m0, bfhi(a0.y), aw);
        ax = fmaf(m1, bflo(a1.x), ax); ay = fmaf(m1, bfhi(a1.x), ay);
        az = fmaf(m1, bflo(a1.y), az); aw = fmaf(m1, bfhi(a1.y), aw);
        ax = fmaf(m2, bflo(a2.x), ax); ay = fmaf(m2, bfhi(a2.x), ay);
        az = fmaf(m2, bflo(a2.y), az); aw = fmaf(m2, bfhi(a2.y), aw);
        ax = fmaf(m3, bflo(a3.x), ax); ay = fmaf(m3, bfhi(a3.x), ay);
        az = fmaf(m3, bflo(a3.y), az); aw = fmaf(m3, bfhi(a3.y), aw);
        ax = fmaf(m4, bflo(a4.x), ax); ay = fmaf(m4, bfhi(a4.x), ay);
        az = fmaf(m4, bflo(a4.y), az); aw = fmaf(m4, bfhi(a4.y), aw);
        ax = fmaf(m5, bflo(a5.x), ax); ay = fmaf(m5, bfhi(a5.x), ay);
        az = fmaf(m5, bflo(a5.y), az); aw = fmaf(m5, bfhi(a5.y), aw);
        ax = fmaf(m6, bflo(a6.x), ax); ay = fmaf(m6, bfhi(a6.x), ay);
        az = fmaf(m6, bflo(a6.y), az); aw = fmaf(m6, bfhi(a6.y), aw);
        ax = fmaf(m7, bflo(a7.x), ax); ay = fmaf(m7, bfhi(a7.x), ay);
        az = fmaf(m7, bflo(a7.y), az); aw = fmaf(m7, bfhi(a7.y), aw);
    }

    // reduce across the 4 edge-groups (lanes t, t+16, t+32, t+48)
#pragma unroll
    for (int m = 16; m <= 32; m <<= 1) {
        ax += __shfl_xor(ax, m, 64);
        ay += __shfl_xor(ay, m, 64);
        az += __shfl_xor(az, m, 64);
        aw += __shfl_xor(aw, m, 64);
    }

    if (g == 0) {
        float inv = 1.0f / fmaxf((float)deg, 1.0f);
        const float4 s = *reinterpret_cast<const float4*>(&S[(size_t)n * DH + t * 4]);
        float4 val;
        val.x = s.x + ax * inv;
        val.y = s.y + ay * inv;
        val.z = s.z + az * inv;
        val.w = s.w + aw * inv;
        if (RELU) {
            val.x = fmaxf(val.x, 0.f); val.y = fmaxf(val.y, 0.f);
            val.z = fmaxf(val.z, 0.f); val.w = fmaxf(val.w, 0.f);
        }
        *reinterpret_cast<float4*>(&H[(size_t)n * DH + t * 4]) = val;
        if (READOUT) {
            int gid = graph_id[n];
            atomicAdd(&gsum[gid * DH + t * 4 + 0], val.x);
            atomicAdd(&gsum[gid * DH + t * 4 + 1], val.y);
            atomicAdd(&gsum[gid * DH + t * 4 + 2], val.z);
            atomicAdd(&gsum[gid * DH + t * 4 + 3], val.w);
            if (t == 0) atomicAdd(&gcnt[gid], 1.0f);
        }
    }
}

// single block of 1024: out_feat = gsum/cnt ; out = out_feat @ W_cls + b_cls
__global__ __launch_bounds__(1024) void readout_kernel(
    const float* __restrict__ gsum, const float* __restrict__ gcnt,
    const float* __restrict__ Wc, const float* __restrict__ bc,
    float* __restrict__ out, float* __restrict__ out_feat) {
    __shared__ float ofs[NG][DH];
    int tid = threadIdx.x;
    int g = tid >> 6, d = tid & 63;
    float of = gsum[tid] / fmaxf(gcnt[g], 1.0f);
    out_feat[tid] = of;
    ofs[g][d] = of;
    __syncthreads();
    if (tid < NG * 2) {
        int gg = tid >> 1, cc = tid & 1;
        float acc = bc[cc];
#pragma unroll 8
        for (int dd = 0; dd < DH; ++dd) acc += ofs[gg][dd] * Wc[dd * 2 + cc];
        out[gg * 2 + cc] = acc;
    }
}

extern "C" void kernel_launch(void* const* d_in, const int* in_sizes, int n_in,
                              void* d_out, int out_size, void* d_ws, size_t ws_size,
                              hipStream_t stream) {
    const float* feat     = (const float*)d_in[0];
    const int*   src      = (const int*)d_in[1];
    const int*   dst      = (const int*)d_in[2];
    const int*   graph_id = (const int*)d_in[3];
    const float* Ws1 = (const float*)d_in[4];
    const float* Wn1 = (const float*)d_in[5];
    const float* b1  = (const float*)d_in[6];
    const float* Ws2 = (const float*)d_in[7];
    const float* Wn2 = (const float*)d_in[8];
    const float* b2  = (const float*)d_in[9];
    const float* Ws3 = (const float*)d_in[10];
    const float* Wn3 = (const float*)d_in[11];
    const float* b3  = (const float*)d_in[12];
    const float* Wc  = (const float*)d_in[13];
    const float* bc  = (const float*)d_in[14];

    const int M = in_sizes[3];   // 10000 nodes
    const int E = in_sizes[1];   // 320000 edges

    float* out      = (float*)d_out;             // 16 x 2
    float* out_feat = out + NG * 2;              // 16 x 64
    float* Hbuf     = out_feat + NG * DH;        // 10000 x 64 (final h)

    // workspace layout (256B-aligned carves: P rows = exactly 2 cache lines)
    char* w = (char*)d_ws;
    size_t off = 0;
    auto carve = [&](size_t bytes) {
        size_t o = off;
        off = (off + bytes + 255) & ~(size_t)255;
        return o;
    };
    int*   deg      = (int*)  (w + carve((size_t)M * 4));
    float* gsum     = (float*)(w + carve((size_t)NG * DH * 4));
    float* gcnt     = (float*)(w + carve((size_t)NG * 4));
    size_t zero_bytes = off;                       // deg + gsum + gcnt
    int*   row_start = (int*)  (w + carve((size_t)(M + 1) * 4));
    int*   cursor    = (int*)  (w + carve((size_t)M * 4));
    int*   edge_src  = (int*)  (w + carve((size_t)E * 4));
    float* Sbuf      = (float*)(w + carve((size_t)M * DH * 4));
    unsigned short* Pbuf = (unsigned short*)(w + carve((size_t)M * DH * 2));
    (void)ws_size; (void)n_in; (void)out_size;

    (void)hipMemsetAsync(d_ws, 0, zero_bytes, stream);

    int eb = (E + 255) / 256;
    deg_count_kernel<<<eb, 256, 0, stream>>>(dst, deg, E);
    scan_kernel<<<1, 1024, 0, stream>>>(deg, row_start, cursor, M);
    scatter_kernel<<<eb, 256, 0, stream>>>(src, dst, cursor, edge_src, E);

    int gb = (M + 63) / 64;   // gemm blocks
    int ab = (M + 3) / 4;     // agg blocks

    // layer 1 (K=256), relu
    gemm_dual_kernel<256><<<gb, 256, 0, stream>>>(feat, Ws1, Wn1, b1, Sbuf, Pbuf, M);
    agg_kernel<true, false><<<ab, 256, 0, stream>>>(Sbuf, Pbuf, row_start, edge_src,
                                                    Hbuf, graph_id, gsum, gcnt, M);
    // layer 2 (K=64), relu
    gemm_dual_kernel<64><<<gb, 256, 0, stream>>>(Hbuf, Ws2, Wn2, b2, Sbuf, Pbuf, M);
    agg_kernel<true, false><<<ab, 256, 0, stream>>>(Sbuf, Pbuf, row_start, edge_src,
                                                    Hbuf, graph_id, gsum, gcnt, M);
    // layer 3 (K=64), no relu, fused readout accumulation
    gemm_dual_kernel<64><<<gb, 256, 0, stream>>>(Hbuf, Ws3, Wn3, b3, Sbuf, Pbuf, M);
    agg_kernel<false, true><<<ab, 256, 0, stream>>>(Sbuf, Pbuf, row_start, edge_src,
                                                    Hbuf, graph_id, gsum, gcnt, M);

    readout_kernel<<<1, 1024, 0, stream>>>(gsum, gcnt, Wc, bc, out, out_feat);
}